// Round 10
// baseline (155.261 us; speedup 1.0000x reference)
//
#include <hip/hip_runtime.h>
#include <hip/hip_bf16.h>

#define Dx 300

// Per-group (=per-XCD) private regions. Group g = xcd_id(): batch b = g>>1,
// row-half h = g&1. All intermediates stay in the group's own L2 — normal
// stores/loads, no sc1, no wbl2, no cross-XCD traffic.
#define GSTRIDE 331776        // floats per group (1.27 MB)
#define EDg     0             // float2[256][300] {exd, rep}  (batch-local rows)
#define HDg     153600        // f32  [256][300]  head        (batch-local rows)
#define ATg     230400        // f32  [128][300]  attn        (half-local rows)
#define UOFFg   268800        // ushort region starts here (float offset)
#define REPBg   0             // bf16 [256][320]              (batch-local rows)
#define ATBg    81920         // bf16 [128][320]              (half-local rows)
#define SYNC_FOFF 2800000     // per-group sync state (memset before launch)

#define AG __HIP_MEMORY_SCOPE_AGENT

// ticket-ordered units per group: 80 mm1 | 160 mm2 | 64 attn | 40 mm3
#define U_MM2 80
#define U_ATT 240
#define U_MM3 304
#define U_TOT 344

typedef __attribute__((ext_vector_type(8))) short short8;
typedef __attribute__((ext_vector_type(4))) float f32x4;

union S8 { unsigned int u[4]; unsigned short s[8]; short8 v; };

__device__ __forceinline__ float bf2f(unsigned short u) {
    union { unsigned int i; float f; } v; v.i = ((unsigned int)u) << 16; return v.f;
}
__device__ __forceinline__ unsigned short f2bf(float x) {   // round-half-up
    union { float f; unsigned int i; } u; u.f = x;
    return (unsigned short)((u.i + 0x8000u) >> 16);
}
__device__ __forceinline__ float ldf(const void* p, int idx, int isbf) {
    return isbf ? bf2f(((const unsigned short*)p)[idx]) : ((const float*)p)[idx];
}

__device__ __forceinline__ void load8f(const float* rowp, int kb, int kmax,
                                       int valid, float* x) {
    if (valid && kb + 8 <= kmax) {
        float4 a = *(const float4*)(rowp + kb);
        float4 b = *(const float4*)(rowp + kb + 4);
        x[0]=a.x; x[1]=a.y; x[2]=a.z; x[3]=a.w;
        x[4]=b.x; x[5]=b.y; x[6]=b.z; x[7]=b.w;
    } else {
        #pragma unroll
        for (int j = 0; j < 8; ++j) {
            int k = kb + j;
            x[j] = (valid && k < kmax) ? rowp[k] : 0.f;
        }
    }
}
__device__ __forceinline__ short8 pack8(const float* x) {
    S8 H;
    #pragma unroll
    for (int p = 0; p < 4; ++p) {
        union { float f; unsigned int i; } a, b;
        a.f = x[2*p]; b.f = x[2*p+1];
        H.u[p] = ((a.i + 0x8000u) >> 16) | ((b.i + 0x8000u) & 0xFFFF0000u);
    }
    return H.v;
}
__device__ __forceinline__ short8 load8bf(const unsigned short* rowp, int kb,
                                          int kmax, int valid) {
    S8 R;
    if (valid && kb + 8 <= kmax) {
        ushort4 a = *(const ushort4*)(rowp + kb);
        ushort4 b = *(const ushort4*)(rowp + kb + 4);
        R.s[0]=a.x; R.s[1]=a.y; R.s[2]=a.z; R.s[3]=a.w;
        R.s[4]=b.x; R.s[5]=b.y; R.s[6]=b.z; R.s[7]=b.w;
    } else {
        #pragma unroll
        for (int j = 0; j < 8; ++j) {
            int k = kb + j;
            R.s[j] = (valid && k < kmax) ? rowp[k] : (unsigned short)0;
        }
    }
    return R.v;
}
__device__ __forceinline__ short8 loadB(const void* W, int row, int kb, int isbf,
                                        int valid) {
    if (isbf) return load8bf((const unsigned short*)W + row * 300, kb, 300, valid);
    float t[8];
    load8f((const float*)W + row * 300, kb, 300, valid, t);
    return pack8(t);
}

__device__ __forceinline__ int xcd_id() {
    int x;
    asm volatile("s_getreg_b32 %0, hwreg(HW_REG_XCC_ID)" : "=s"(x));
    return x & 7;
}
// relaxed spin (L2-local line); bounded => lost block = visible verify fail
__device__ __forceinline__ void spin_ge(int* p, int target) {
    int t = 0;
    while (__hip_atomic_load(p, __ATOMIC_RELAXED, AG) < target) {
        __builtin_amdgcn_s_sleep(1);
        if (++t > 500000) break;
    }
    asm volatile("" ::: "memory");
}

// Per-group sync slots (ints, 128 B apart), S = base + g*1024:
//   ticket   S[0]
//   cnt1[mt] S[32 + mt*32]   (mt 0..15, target 5)
//   cnt2     S[576]          (target 160)
//   cnt3[t]  S[640 + t*32]   (t 0..7, target = valid rows in tile)

// ---------------------------------------------------------------------------
// XCD-local DiSA: each group (XCD) computes mm1+mm2 for its FULL batch into
// private L2-resident buffers (duplicated across the sibling — MFMA is ~free),
// then attn+mm3 for its row-half. No cross-XCD data edges at all.
// grid 768 x 320 (3 blocks/CU => all resident, ~96 blocks/XCD).
// ---------------------------------------------------------------------------
__global__ __launch_bounds__(320, 4) void k_fused(
        const void* __restrict__ Xv, const int* __restrict__ mask,
        const void* __restrict__ Wfc, const void* __restrict__ bfc,
        const void* __restrict__ W1,  const void* __restrict__ W2,
        const void* __restrict__ b1v, const void* __restrict__ Wf1,
        const void* __restrict__ Wf2, const void* __restrict__ bfv,
        float* __restrict__ ws, void* __restrict__ outv) {
    __shared__ int s_isbf, s_u, s_cnt, s_c128;
    __shared__ int s_tgt3[8];
    __shared__ unsigned short vlist[256];

    const int tid = threadIdx.x;
    // wave-parallel bf16 detect
    if (tid < 64) {
        float v = bf2f(((const unsigned short*)Wfc)[tid]);
        int ok = fabsf(v) < 1.0f;
        unsigned long long bal = __ballot(ok);
        if (tid == 0) s_isbf = (bal == ~0ull) ? 1 : 0;
    }
    if (tid >= 64 && tid < 72) s_tgt3[tid - 64] = 0;
    __syncthreads();
    const int isbf = s_isbf;

    const int g = xcd_id();
    const int b = g >> 1, h = g & 1;
    const int base = b * 256, rbase = base + h * 128;
    float* G = ws + (size_t)g * GSTRIDE;
    unsigned short* U = (unsigned short*)(G + UOFFg);
    int* S = (int*)(ws + SYNC_FOFF) + g * 1024;

    // build batch vlist (sorted, batch-local j values 0..255); own rows are
    // the contiguous range [lo,hi) of vlist
    if (tid < 64) {
        int basec = 0;
        #pragma unroll
        for (int c = 0; c < 4; ++c) {
            const int j = c * 64 + tid;
            const int mv = mask[base + j] != 0;
            unsigned long long bal = __ballot(mv);
            int pos = basec + __popcll(bal & ((1ull << tid) - 1ull));
            if (mv) vlist[pos] = (unsigned short)j;
            basec += __popcll(bal);
            if (c == 1 && tid == 0) s_c128 = basec;
        }
        if (tid == 0) s_cnt = basec;
    }
    __syncthreads();
    const int cnt = s_cnt;
    const int lo = h ? s_c128 : 0;
    const int hi = h ? cnt : s_c128;
    if (tid < 128) {                     // per-16-row-tile valid counts
        const int k = lo + tid;
        if (k < hi) atomicAdd(&s_tgt3[((int)vlist[k] - h * 128) >> 4], 1);
    }
    __syncthreads();

    // ---------------- ticket loop (dependency-ordered units) ----------------
    for (;;) {
        __syncthreads();
        if (tid == 0)
            s_u = __hip_atomic_fetch_add(S, 1, __ATOMIC_RELAXED, AG);
        __syncthreads();
        const int u = s_u;
        if (u >= U_TOT) break;

        if (u < U_MM2) {
            // ---- mm1 unit: rep = elu(X@Wfc^T+bfc), 16 rows x 64 cols ----
            const int mt = u / 5, nt = u % 5;
            if (tid < 256) {
                const int w = tid >> 6, l = tid & 63;
                const int lm = l & 15, koff = (l >> 4) * 8;
                const int nrow = nt * 64 + w * 16 + lm;      // 0..319
                const int bval = nrow < 300;
                const int ncl = bval ? nrow : 0;
                f32x4 acc = {0.f, 0.f, 0.f, 0.f};
                const int arow = base + mt * 16 + lm;        // global X row
                if (isbf) {
                    const unsigned short* Xp = (const unsigned short*)Xv + arow * 300;
                    #pragma unroll
                    for (int ks = 0; ks < 10; ++ks) {
                        short8 a = load8bf(Xp, ks*32 + koff, 300, 1);
                        short8 bb = loadB(Wfc, ncl, ks*32 + koff, 1, bval);
                        acc = __builtin_amdgcn_mfma_f32_16x16x32_bf16(a, bb, acc, 0, 0, 0);
                    }
                } else {
                    const float* Xp = (const float*)Xv + arow * 300;
                    #pragma unroll
                    for (int ks = 0; ks < 10; ++ks) {
                        float t[8]; load8f(Xp, ks*32 + koff, 300, 1, t);
                        short8 a = pack8(t);
                        short8 bb = loadB(Wfc, ncl, ks*32 + koff, 0, bval);
                        acc = __builtin_amdgcn_mfma_f32_16x16x32_bf16(a, bb, acc, 0, 0, 0);
                    }
                }
                if (bval) {
                    float bb = ldf(bfc, nrow, isbf);
                    #pragma unroll
                    for (int r = 0; r < 4; ++r) {
                        const int lr = mt * 16 + (l >> 4) * 4 + r;   // batch-local
                        float v = acc[r] + bb;
                        v = v > 0.f ? v : (__expf(v) - 1.f);
                        G[EDg + (lr * 300 + nrow) * 2 + 1] = v;      // ed.y = rep
                        U[REPBg + lr * 320 + nrow] = f2bf(v);
                    }
                } else {
                    #pragma unroll
                    for (int r = 0; r < 4; ++r) {
                        const int lr = mt * 16 + (l >> 4) * 4 + r;
                        U[REPBg + lr * 320 + nrow] = 0;
                    }
                }
            }
            __syncthreads();                         // drain stores to L2
            if (tid == 0)
                __hip_atomic_fetch_add(S + 32 + mt * 32, 1, __ATOMIC_RELAXED, AG);

        } else if (u < U_ATT) {
            // ---- mm2 unit: dep/head = rep @ {W1,W2}^T, 16 rows x 64 cols ----
            const int q = u - U_MM2, mt = q / 10, nt10 = q % 10;
            if (tid == 0) spin_ge(S + 32 + mt * 32, 5);
            __syncthreads();
            if (tid < 256) {
                const int w = tid >> 6, l = tid & 63;
                const int lm = l & 15, koff = (l >> 4) * 8;
                const int ng = nt10 * 64 + w * 16 + lm;      // 0..639
                const int wsel = ng < 320;
                const int wrow = wsel ? ng : ng - 320;
                const int bval = wrow < 300;
                const int ncl = bval ? wrow : 0;
                const void* Wsel = wsel ? W1 : W2;
                const unsigned short* ap = U + REPBg + (mt * 16 + lm) * 320 + koff;
                f32x4 acc = {0.f, 0.f, 0.f, 0.f};
                #pragma unroll
                for (int ks = 0; ks < 10; ++ks) {
                    short8 a = *(const short8*)(ap + ks * 32);
                    short8 bb = loadB(Wsel, ncl, ks*32 + koff, isbf, bval);
                    acc = __builtin_amdgcn_mfma_f32_16x16x32_bf16(a, bb, acc, 0, 0, 0);
                }
                if (ng < 300) {
                    float bb = ldf(b1v, ng, isbf);
                    #pragma unroll
                    for (int r = 0; r < 4; ++r) {
                        const int lr = mt * 16 + (l >> 4) * 4 + r;
                        G[EDg + (lr * 300 + ng) * 2] = __expf(0.4f * (acc[r] + bb));
                    }
                } else if (ng >= 320 && ng < 620) {
                    #pragma unroll
                    for (int r = 0; r < 4; ++r) {
                        const int lr = mt * 16 + (l >> 4) * 4 + r;
                        G[HDg + lr * 300 + (ng - 320)] = acc[r];
                    }
                }
            }
            __syncthreads();
            if (tid == 0)
                __hip_atomic_fetch_add(S + 576, 1, __ATOMIC_RELAXED, AG);

        } else if (u < U_MM3) {
            // ---- attn unit: 2 consecutive own valid rows ----
            const int p = u - U_ATT;
            const int iu = lo + 2 * p;
            if (iu < hi) {
                if (tid == 0) spin_ge(S + 576, 160);
                __syncthreads();
                const int ia = vlist[iu];                    // batch-local row
                const int hasB = (iu + 1 < hi);
                const int ib = hasB ? vlist[iu + 1] : ia;
                const int ha = ia - h * 128, hb = ib - h * 128;  // half-local
                const int d = tid;
                if (d >= 300) {
                    U[ATBg + ha * 320 + d] = 0;
                    U[ATBg + hb * 320 + d] = 0;
                } else {
                    const float pwa = __expf(0.4f * G[HDg + ia * 300 + d]);
                    const float pwb = __expf(0.4f * G[HDg + ib * 300 + d]);
                    const float2* ep2 = ((const float2*)(G + EDg)) + d;
                    float sa = 0.f, ra = 0.f, sb = 0.f, rb = 0.f;
                    if (iu + 1 < cnt) {              // row A's first j
                        const int j = vlist[iu + 1];
                        float2 v = ep2[j * 300];
                        float ua = fmaf(v.x, pwa, 1.0f);
                        float ea = __expf(-10.0f * __builtin_amdgcn_rcpf(ua));
                        sa += ea; ra = fmaf(ea, v.y, ra);
                    }
                    #pragma unroll 16
                    for (int t = iu + 2; t < cnt; ++t) {
                        const int j = vlist[t];
                        float2 v = ep2[j * 300];
                        float ua = fmaf(v.x, pwa, 1.0f);
                        float ub = fmaf(v.x, pwb, 1.0f);
                        float ea = __expf(-10.0f * __builtin_amdgcn_rcpf(ua));
                        float eb = __expf(-10.0f * __builtin_amdgcn_rcpf(ub));
                        sa += ea; ra = fmaf(ea, v.y, ra);
                        sb += eb; rb = fmaf(eb, v.y, rb);
                    }
                    const float dena = sa + (sa == 0.f ? 1.f : 0.f) + 1e-20f;
                    const float aa = ra / dena;
                    G[ATg + ha * 300 + d] = aa;
                    U[ATBg + ha * 320 + d] = f2bf(aa);
                    if (hasB) {
                        const float denb = sb + (sb == 0.f ? 1.f : 0.f) + 1e-20f;
                        const float ab = rb / denb;
                        G[ATg + hb * 300 + d] = ab;
                        U[ATBg + hb * 320 + d] = f2bf(ab);
                    }
                }
                __syncthreads();
                if (tid == 0) {
                    __hip_atomic_fetch_add(S + 640 + (ha >> 4) * 32, 1,
                                           __ATOMIC_RELAXED, AG);
                    if (hasB)
                        __hip_atomic_fetch_add(S + 640 + (hb >> 4) * 32, 1,
                                               __ATOMIC_RELAXED, AG);
                }
            }

        } else {
            // ---- mm3 unit: gate+blend for 16 own rows x 64 cols ----
            const int m = u - U_MM3, mt3 = m / 5, nt3 = m % 5;
            const int tgt = s_tgt3[mt3];
            if (tid == 0 && tgt > 0) spin_ge(S + 640 + mt3 * 32, tgt);
            __syncthreads();
            if (tid < 256) {
                const int w = tid >> 6, l = tid & 63;
                const int lm = l & 15, koff = (l >> 4) * 8;
                const int nrow = nt3 * 64 + w * 16 + lm;     // 0..319
                const int bval = nrow < 300;
                const int ncl = bval ? nrow : 0;
                const unsigned short* a1p = U + REPBg + (h * 128 + mt3 * 16 + lm) * 320 + koff;
                const unsigned short* a2p = U + ATBg + (mt3 * 16 + lm) * 320 + koff;
                f32x4 acc = {0.f, 0.f, 0.f, 0.f};
                #pragma unroll
                for (int ks = 0; ks < 10; ++ks) {
                    short8 a = *(const short8*)(a1p + ks * 32);
                    short8 bb = loadB(Wf1, ncl, ks*32 + koff, isbf, bval);
                    acc = __builtin_amdgcn_mfma_f32_16x16x32_bf16(a, bb, acc, 0, 0, 0);
                }
                #pragma unroll
                for (int ks = 0; ks < 10; ++ks) {
                    short8 a = *(const short8*)(a2p + ks * 32);
                    short8 bb = loadB(Wf2, ncl, ks*32 + koff, isbf, bval);
                    acc = __builtin_amdgcn_mfma_f32_16x16x32_bf16(a, bb, acc, 0, 0, 0);
                }
                if (bval) {
                    float bb = ldf(bfv, nrow, isbf);
                    #pragma unroll
                    for (int r = 0; r < 4; ++r) {
                        const int mgl = mt3 * 16 + (l >> 4) * 4 + r;  // half-local
                        const int gr = rbase + mgl;                   // global row
                        float res = 0.f;
                        if (mask[gr]) {
                            float gp = acc[r] + bb;
                            float gate = 1.0f / (1.0f + __expf(-gp));
                            float rv = G[EDg + ((h * 128 + mgl) * 300 + nrow) * 2 + 1];
                            float av = G[ATg + mgl * 300 + nrow];
                            res = gate * rv + (1.0f - gate) * av;
                        }
                        if (isbf) ((__hip_bfloat16*)outv)[gr * 300 + nrow] = __float2bfloat16(res);
                        else      ((float*)outv)[gr * 300 + nrow] = res;
                    }
                }
            }
        }
    }
}

extern "C" void kernel_launch(void* const* d_in, const int* in_sizes, int n_in,
                              void* d_out, int out_size, void* d_ws, size_t ws_size,
                              hipStream_t stream) {
    const void* X   = d_in[0];
    const int*  msk = (const int*)d_in[1];
    const void* Wfc = d_in[2];
    const void* bfc = d_in[3];
    const void* W1  = d_in[4];
    const void* W2  = d_in[5];
    const void* b1  = d_in[6];
    const void* Wf1 = d_in[7];
    const void* Wf2 = d_in[8];
    const void* bfv = d_in[9];
    float* ws = (float*)d_ws;

    // zero the per-group sync state (8 groups x 4 KB)
    hipMemsetAsync((char*)d_ws + (size_t)SYNC_FOFF * sizeof(float), 0, 32768, stream);

    hipLaunchKernelGGL(k_fused, dim3(768), dim3(320), 0, stream,
                       X, msk, Wfc, bfc, W1, W2, b1, Wf1, Wf2, bfv, ws, d_out);
}

// Round 11
// 114.192 us; speedup vs baseline: 1.3597x; 1.3597x over previous
//
#include <hip/hip_runtime.h>
#include <hip/hip_bf16.h>

#define Dx 300

// float-offsets into ws. All inter-block intermediates written with sc0/sc1
// write-through (coherence point); consumers first-touch after their flag.
#define ED     0             // float2 [1024][300] {exd, rep}
#define HEADF  614400        // f32 [1024][300]
#define ATTNF  921600        // f32 [1024][300]
#define U_BASE 1228800       // ushort region (float offset)
#define REPB   0             // bf16 [1024][320]
#define ATB    327680        // bf16 [1024][320]
#define SYNC_FOFF 2000000    // flag state (memset before launch)

#define AG __HIP_MEMORY_SCOPE_AGENT

typedef __attribute__((ext_vector_type(8))) short short8;
typedef __attribute__((ext_vector_type(4))) float f32x4;

union S8 { unsigned int u[4]; unsigned short s[8]; short8 v; };

__device__ __forceinline__ float bf2f(unsigned short u) {
    union { unsigned int i; float f; } v; v.i = ((unsigned int)u) << 16; return v.f;
}
__device__ __forceinline__ unsigned short f2bf(float x) {   // round-half-up
    union { float f; unsigned int i; } u; u.f = x;
    return (unsigned short)((u.i + 0x8000u) >> 16);
}
__device__ __forceinline__ float ldf(const void* p, int idx, int isbf) {
    return isbf ? bf2f(((const unsigned short*)p)[idx]) : ((const float*)p)[idx];
}

// write-through stores (visible at coherence point once vmcnt acks)
__device__ __forceinline__ void st_wt_f32(float* p, float v) {
    asm volatile("global_store_dword %0, %1, off sc0 sc1"
                 :: "v"(p), "v"(v) : "memory");
}
__device__ __forceinline__ void st_wt_u16(unsigned short* p, unsigned short v) {
    unsigned int vv = v;
    asm volatile("global_store_short %0, %1, off sc0 sc1"
                 :: "v"(p), "v"(vv) : "memory");
}

__device__ __forceinline__ void load8f(const float* rowp, int kb, int kmax,
                                       int valid, float* x) {
    if (valid && kb + 8 <= kmax) {
        float4 a = *(const float4*)(rowp + kb);
        float4 b = *(const float4*)(rowp + kb + 4);
        x[0]=a.x; x[1]=a.y; x[2]=a.z; x[3]=a.w;
        x[4]=b.x; x[5]=b.y; x[6]=b.z; x[7]=b.w;
    } else {
        #pragma unroll
        for (int j = 0; j < 8; ++j) {
            int k = kb + j;
            x[j] = (valid && k < kmax) ? rowp[k] : 0.f;
        }
    }
}
__device__ __forceinline__ short8 pack8(const float* x) {
    S8 H;
    #pragma unroll
    for (int p = 0; p < 4; ++p) {
        union { float f; unsigned int i; } a, b;
        a.f = x[2*p]; b.f = x[2*p+1];
        H.u[p] = ((a.i + 0x8000u) >> 16) | ((b.i + 0x8000u) & 0xFFFF0000u);
    }
    return H.v;
}
__device__ __forceinline__ short8 load8bf(const unsigned short* rowp, int kb,
                                          int kmax, int valid) {
    S8 R;
    if (valid && kb + 8 <= kmax) {
        ushort4 a = *(const ushort4*)(rowp + kb);
        ushort4 b = *(const ushort4*)(rowp + kb + 4);
        R.s[0]=a.x; R.s[1]=a.y; R.s[2]=a.z; R.s[3]=a.w;
        R.s[4]=b.x; R.s[5]=b.y; R.s[6]=b.z; R.s[7]=b.w;
    } else {
        #pragma unroll
        for (int j = 0; j < 8; ++j) {
            int k = kb + j;
            R.s[j] = (valid && k < kmax) ? rowp[k] : (unsigned short)0;
        }
    }
    return R.v;
}
__device__ __forceinline__ short8 loadB(const void* W, int row, int kb, int isbf,
                                        int valid) {
    if (isbf) return load8bf((const unsigned short*)W + row * 300, kb, 300, valid);
    float t[8];
    load8f((const float*)W + row * 300, kb, 300, valid, t);
    return pack8(t);
}

__device__ __forceinline__ int xcd_id() {
    int x;
    asm volatile("s_getreg_b32 %0, hwreg(HW_REG_XCC_ID)" : "=s"(x));
    return x & 7;
}
// relaxed spin until *p >= target; bounded (lost block => visible fail)
__device__ __forceinline__ void spin_ge(int* p, int target) {
    int t = 0;
    while (__hip_atomic_load(p, __ATOMIC_RELAXED, AG) < target) {
        __builtin_amdgcn_s_sleep(1);
        if (++t > 500000) break;
    }
    asm volatile("" ::: "memory");
}

// SYNC slots (int index, 256 B apart):
//   cnt1[mt]  = mt*64           mm1 tiles (target 5)
//   cnt2[b]   = (64+b)*64       mm2 units per batch (target 160)
//   fb[b][x]  = (68+b*8+x)*64   per-XCD fan-out flags
//   cnt3[gt]  = (100+gt)*64     attn rows done per global 16-row tile

// ---------------------------------------------------------------------------
// Fused DiSA, flag-chained, XCD-PAIR BATCH SWIZZLE (T1-style): presumed
// XCD = blk&7; batch bat = (blk&7)>>1 so batch b's entire pipeline runs on
// XCD pair {2b,2b+1} — intermediates fetched <=2x instead of ~8x, reads
// become L2 hits. Pure index remap of round-9's kernel; flags/sc1 unchanged,
// so a wrong XCD mapping costs speed only, never correctness.
// Per batch: li = (blk>>3)*2 + (blk&1) in 0..159.
//   mm1: li<80  -> (mt_local=li/5, nt=li%5)
//   mm2: all li -> (mt_local=li/10, nt10=li%10)
//   attn: pair (2*li, 2*li+1) of vlist while 2*li < cnt
//   mm3: li<80  -> (mt3_local=li/5, nt3=li%5)
// grid 640 x 320 (3 blocks/CU => co-resident).
// ---------------------------------------------------------------------------
__global__ __launch_bounds__(320, 4) void k_fused(
        const void* __restrict__ Xv, const int* __restrict__ mask,
        const void* __restrict__ Wfc, const void* __restrict__ bfc,
        const void* __restrict__ W1,  const void* __restrict__ W2,
        const void* __restrict__ b1v, const void* __restrict__ Wf1,
        const void* __restrict__ Wf2, const void* __restrict__ bfv,
        float* __restrict__ ws, void* __restrict__ outv) {
    __shared__ int s_isbf;
    __shared__ unsigned short vlist[256];
    __shared__ int s_cnt, s_tgt;

    const int tid = threadIdx.x;
    const int blk = blockIdx.x;
    // wave-parallel bf16 detect (1 load latency)
    if (tid < 64) {
        float v = bf2f(((const unsigned short*)Wfc)[tid]);
        int ok = fabsf(v) < 1.0f;
        unsigned long long bal = __ballot(ok);
        if (tid == 0) s_isbf = (bal == ~0ull) ? 1 : 0;
    }
    __syncthreads();
    const int isbf = s_isbf;
    unsigned short* U = (unsigned short*)(ws + U_BASE);
    int* S = (int*)(ws + SYNC_FOFF);
    const int xid = xcd_id();

    // swizzle: batch <-> XCD pair
    const int res = blk & 7;
    const int bat = res >> 1;            // 0..3
    const int li  = ((blk >> 3) << 1) | (res & 1);   // 0..159 within batch
    const int base = bat * 256;

    // ---- Phase 1: mm1  rep = elu(X@Wfc^T + bfc)  (li < 80) ----
    if (li < 80 && tid < 256) {
        const int mt_l = li / 5, nt = li % 5;
        const int mt = bat * 16 + mt_l;
        const int w = tid >> 6, l = tid & 63;
        const int m0 = mt * 16, lm = l & 15, koff = (l >> 4) * 8;
        const int nrow = nt * 64 + w * 16 + lm;          // 0..319
        const int bval = nrow < 300;
        const int ncl = bval ? nrow : 0;
        f32x4 acc = {0.f, 0.f, 0.f, 0.f};
        if (isbf) {
            const unsigned short* Xp = (const unsigned short*)Xv + (m0 + lm) * 300;
            #pragma unroll
            for (int ks = 0; ks < 10; ++ks) {
                short8 a = load8bf(Xp, ks*32 + koff, 300, 1);
                short8 b = loadB(Wfc, ncl, ks*32 + koff, 1, bval);
                acc = __builtin_amdgcn_mfma_f32_16x16x32_bf16(a, b, acc, 0, 0, 0);
            }
        } else {
            const float* Xp = (const float*)Xv + (m0 + lm) * 300;
            #pragma unroll
            for (int ks = 0; ks < 10; ++ks) {
                float t[8]; load8f(Xp, ks*32 + koff, 300, 1, t);
                short8 a = pack8(t);
                short8 b = loadB(Wfc, ncl, ks*32 + koff, 0, bval);
                acc = __builtin_amdgcn_mfma_f32_16x16x32_bf16(a, b, acc, 0, 0, 0);
            }
        }
        if (bval) {
            float bb = ldf(bfc, nrow, isbf);
            #pragma unroll
            for (int r = 0; r < 4; ++r) {
                int mg = m0 + (l >> 4) * 4 + r;
                float v = acc[r] + bb;
                v = v > 0.f ? v : (__expf(v) - 1.f);
                st_wt_f32(ws + ED + (mg * 300 + nrow) * 2 + 1, v);  // ed.y = rep
                st_wt_u16(U + REPB + mg * 320 + nrow, f2bf(v));
            }
        } else {
            #pragma unroll
            for (int r = 0; r < 4; ++r) {
                int mg = m0 + (l >> 4) * 4 + r;
                st_wt_u16(U + REPB + mg * 320 + nrow, 0);
            }
        }
    }
    __syncthreads();                                // drains all waves' vmcnt
    if (li < 80 && tid == 0)
        __hip_atomic_fetch_add(S + (bat * 16 + li / 5) * 64, 1,
                               __ATOMIC_RELAXED, AG);

    // ---- Phase 2: mm2  dep/head = rep @ {W1,W2}^T; one unit per block ----
    {
        const int mt_l = li / 10, nt10 = li % 10;
        const int mt = bat * 16 + mt_l;
        if (tid == 0) spin_ge(S + mt * 64, 5);
        __syncthreads();
        if (tid < 256) {
            const int w = tid >> 6, l = tid & 63;
            const int m0 = mt * 16, lm = l & 15, koff = (l >> 4) * 8;
            const int ng = nt10 * 64 + w * 16 + lm;      // 0..639
            const int wsel = ng < 320;
            const int wrow = wsel ? ng : ng - 320;
            const int bval = wrow < 300;
            const int ncl = bval ? wrow : 0;
            const void* Wsel = wsel ? W1 : W2;
            const unsigned short* ap = U + REPB + (m0 + lm) * 320 + koff;
            f32x4 acc = {0.f, 0.f, 0.f, 0.f};
            #pragma unroll
            for (int ks = 0; ks < 10; ++ks) {
                short8 a = *(const short8*)(ap + ks * 32);
                short8 b = loadB(Wsel, ncl, ks*32 + koff, isbf, bval);
                acc = __builtin_amdgcn_mfma_f32_16x16x32_bf16(a, b, acc, 0, 0, 0);
            }
            if (ng < 300) {
                float bb = ldf(b1v, ng, isbf);
                #pragma unroll
                for (int r = 0; r < 4; ++r) {
                    int mg = m0 + (l >> 4) * 4 + r;
                    st_wt_f32(ws + ED + (mg * 300 + ng) * 2,
                              __expf(0.4f * (acc[r] + bb)));   // ed.x
                }
            } else if (ng >= 320 && ng < 620) {
                #pragma unroll
                for (int r = 0; r < 4; ++r) {
                    int mg = m0 + (l >> 4) * 4 + r;
                    st_wt_f32(ws + HEADF + mg * 300 + (ng - 320), acc[r]);
                }
            }
        }
        __syncthreads();                        // drain before flag
        if (tid == 0) {
            int old = __hip_atomic_fetch_add(S + (64 + bat) * 64, 1,
                                             __ATOMIC_RELAXED, AG);
            if (old == 159) {                   // last mm2 unit of batch
                #pragma unroll
                for (int x = 0; x < 8; ++x)
                    __hip_atomic_store(S + (68 + bat * 8 + x) * 64, 1,
                                       __ATOMIC_RELAXED, AG);
            }
        }
    }

    // ---- Phase 3: attn; compacted valid rows, pair (2*li, 2*li+1).
    //      For row vlist[k], valid-j start is index k+1 (vlist sorted). ----
    {
        // build vlist first (mask is kernel input — overlaps the fb wait)
        if (tid < 64) {
            int basec = 0;
            #pragma unroll
            for (int c = 0; c < 4; ++c) {
                const int j = c * 64 + tid;
                const int mv = mask[base + j] != 0;
                unsigned long long bal = __ballot(mv);
                int pos = basec + __popcll(bal & ((1ull << tid) - 1ull));
                if (mv) vlist[pos] = (unsigned short)j;
                basec += __popcll(bal);
            }
            if (tid == 0) s_cnt = basec;
        }
        if (tid == 0) spin_ge(S + (68 + bat * 8 + xid) * 64, 1);
        __syncthreads();
        const int cnt = s_cnt;
        const int iu = 2 * li;
        if (iu < cnt) {
            const int ia = vlist[iu];                    // valid row A
            const int hasB = (iu + 1 < cnt);
            const int ib = hasB ? vlist[iu + 1] : ia;    // valid row B
            const int ga = base + ia, gb = base + ib;
            const int d = tid;
            if (d >= 300) {
                st_wt_u16(U + ATB + ga * 320 + d, 0);
                if (hasB) st_wt_u16(U + ATB + gb * 320 + d, 0);
            } else {
                const float pwa = __expf(0.4f * ws[HEADF + ga * 300 + d]);
                const float pwb = __expf(0.4f * ws[HEADF + gb * 300 + d]);
                const float2* ep2 = ((const float2*)(ws + ED)) + base * Dx + d;
                float sa = 0.f, ra = 0.f, sb = 0.f, rb = 0.f;
                if (hasB) {                              // prologue: j=vlist[iu+1]
                    const int j = ib;                    // row A only (j > ia)
                    float2 v = ep2[j * Dx];
                    float ua = fmaf(v.x, pwa, 1.0f);
                    float ea = __expf(-10.0f * __builtin_amdgcn_rcpf(ua));
                    sa += ea; ra = fmaf(ea, v.y, ra);
                }
                #pragma unroll 16
                for (int t = iu + 2; t < cnt; ++t) {
                    const int j = vlist[t];
                    float2 v = ep2[j * Dx];
                    float ua = fmaf(v.x, pwa, 1.0f);
                    float ub = fmaf(v.x, pwb, 1.0f);
                    float ea = __expf(-10.0f * __builtin_amdgcn_rcpf(ua));
                    float eb = __expf(-10.0f * __builtin_amdgcn_rcpf(ub));
                    sa += ea; ra = fmaf(ea, v.y, ra);
                    sb += eb; rb = fmaf(eb, v.y, rb);
                }
                const float dena = sa + (sa == 0.f ? 1.f : 0.f) + 1e-20f;
                const float aa = ra / dena;
                st_wt_f32(ws + ATTNF + ga * Dx + d, aa);
                st_wt_u16(U + ATB + ga * 320 + d, f2bf(aa));
                if (hasB) {
                    const float denb = sb + (sb == 0.f ? 1.f : 0.f) + 1e-20f;
                    const float ab = rb / denb;
                    st_wt_f32(ws + ATTNF + gb * Dx + d, ab);
                    st_wt_u16(U + ATB + gb * 320 + d, f2bf(ab));
                }
            }
            __syncthreads();                    // drain before row flags
            if (tid == 0) {
                __hip_atomic_fetch_add(S + (100 + (ga >> 4)) * 64, 1,
                                       __ATOMIC_RELAXED, AG);
                if (hasB)
                    __hip_atomic_fetch_add(S + (100 + (gb >> 4)) * 64, 1,
                                           __ATOMIC_RELAXED, AG);
            }
        }
    }

    // ---- Phase 4: mm3 (li < 80); gate = data-dependent valid count ----
    if (li < 80) {
        const int mt3 = bat * 16 + li / 5, nt3 = li % 5;
        const int m0 = mt3 * 16;
        if (tid < 64) {
            int mv = (tid < 16) ? (mask[m0 + tid] != 0) : 0;
            unsigned long long bal = __ballot(mv);
            if (tid == 0) s_tgt = (int)__popcll(bal);
        }
        __syncthreads();
        const int tgt = s_tgt;
        if (tid == 0 && tgt > 0) spin_ge(S + (100 + mt3) * 64, tgt);
        __syncthreads();
        if (tid < 256) {
            const int w = tid >> 6, l = tid & 63;
            const int lm = l & 15, koff = (l >> 4) * 8;
            const int nrow = nt3 * 64 + w * 16 + lm;     // 0..319
            const int bval = nrow < 300;
            const int ncl = bval ? nrow : 0;
            const unsigned short* a1p = U + REPB + (m0 + lm) * 320 + koff;
            const unsigned short* a2p = U + ATB  + (m0 + lm) * 320 + koff;
            f32x4 acc = {0.f, 0.f, 0.f, 0.f};
            #pragma unroll
            for (int ks = 0; ks < 10; ++ks) {
                short8 a = *(const short8*)(a1p + ks * 32);
                short8 bB = loadB(Wf1, ncl, ks*32 + koff, isbf, bval);
                acc = __builtin_amdgcn_mfma_f32_16x16x32_bf16(a, bB, acc, 0, 0, 0);
            }
            #pragma unroll
            for (int ks = 0; ks < 10; ++ks) {
                short8 a = *(const short8*)(a2p + ks * 32);
                short8 bB = loadB(Wf2, ncl, ks*32 + koff, isbf, bval);
                acc = __builtin_amdgcn_mfma_f32_16x16x32_bf16(a, bB, acc, 0, 0, 0);
            }
            if (bval) {
                float bb = ldf(bfv, nrow, isbf);
                #pragma unroll
                for (int r = 0; r < 4; ++r) {
                    int mg = m0 + (l >> 4) * 4 + r;
                    float res2 = 0.f;
                    if (mask[mg]) {
                        float gp = acc[r] + bb;
                        float gate = 1.0f / (1.0f + __expf(-gp));
                        float rv = ws[ED + (mg * 300 + nrow) * 2 + 1];
                        float av = ws[ATTNF + mg * 300 + nrow];
                        res2 = gate * rv + (1.0f - gate) * av;
                    }
                    if (isbf) ((__hip_bfloat16*)outv)[mg * 300 + nrow] = __float2bfloat16(res2);
                    else      ((float*)outv)[mg * 300 + nrow] = res2;
                }
            }
        }
    }
}

extern "C" void kernel_launch(void* const* d_in, const int* in_sizes, int n_in,
                              void* d_out, int out_size, void* d_ws, size_t ws_size,
                              hipStream_t stream) {
    const void* X   = d_in[0];
    const int*  msk = (const int*)d_in[1];
    const void* Wfc = d_in[2];
    const void* bfc = d_in[3];
    const void* W1  = d_in[4];
    const void* W2  = d_in[5];
    const void* b1  = d_in[6];
    const void* Wf1 = d_in[7];
    const void* Wf2 = d_in[8];
    const void* bfv = d_in[9];
    float* ws = (float*)d_ws;

    // zero the flag state (192 slots x 256 B)
    hipMemsetAsync((char*)d_ws + (size_t)SYNC_FOFF * sizeof(float), 0, 49152, stream);

    hipLaunchKernelGGL(k_fused, dim3(640), dim3(320), 0, stream,
                       X, msk, Wfc, bfc, W1, W2, b1, Wf1, Wf2, bfv, ws, d_out);
}

// Round 12
// 112.461 us; speedup vs baseline: 1.3806x; 1.0154x over previous
//
#include <hip/hip_runtime.h>
#include <hip/hip_bf16.h>

#define Dx 300

// float-offsets into ws. All inter-block intermediates written with sc0/sc1
// write-through (coherence point); consumers first-touch after their flag.
#define ED     0             // float2 [1024][300] {exd, rep}
#define HEADF  614400        // f32 [1024][300]
#define ATTNF  921600        // f32 [1024][300]
#define U_BASE 1228800       // ushort region (float offset)
#define REPB   0             // bf16 [1024][320]
#define ATB    327680        // bf16 [1024][320]
#define SYNC_FOFF 2000000    // flag state (memset before launch)

#define AG __HIP_MEMORY_SCOPE_AGENT

typedef __attribute__((ext_vector_type(8))) short short8;
typedef __attribute__((ext_vector_type(4))) float f32x4;

union S8 { unsigned int u[4]; unsigned short s[8]; short8 v; };

__device__ __forceinline__ float bf2f(unsigned short u) {
    union { unsigned int i; float f; } v; v.i = ((unsigned int)u) << 16; return v.f;
}
__device__ __forceinline__ unsigned short f2bf(float x) {   // round-half-up
    union { float f; unsigned int i; } u; u.f = x;
    return (unsigned short)((u.i + 0x8000u) >> 16);
}
__device__ __forceinline__ float ldf(const void* p, int idx, int isbf) {
    return isbf ? bf2f(((const unsigned short*)p)[idx]) : ((const float*)p)[idx];
}

// write-through stores (visible at coherence point once vmcnt acks)
__device__ __forceinline__ void st_wt_f32(float* p, float v) {
    asm volatile("global_store_dword %0, %1, off sc0 sc1"
                 :: "v"(p), "v"(v) : "memory");
}
__device__ __forceinline__ void st_wt_u16(unsigned short* p, unsigned short v) {
    unsigned int vv = v;
    asm volatile("global_store_short %0, %1, off sc0 sc1"
                 :: "v"(p), "v"(vv) : "memory");
}

__device__ __forceinline__ void load8f(const float* rowp, int kb, int kmax,
                                       int valid, float* x) {
    if (valid && kb + 8 <= kmax) {
        float4 a = *(const float4*)(rowp + kb);
        float4 b = *(const float4*)(rowp + kb + 4);
        x[0]=a.x; x[1]=a.y; x[2]=a.z; x[3]=a.w;
        x[4]=b.x; x[5]=b.y; x[6]=b.z; x[7]=b.w;
    } else {
        #pragma unroll
        for (int j = 0; j < 8; ++j) {
            int k = kb + j;
            x[j] = (valid && k < kmax) ? rowp[k] : 0.f;
        }
    }
}
__device__ __forceinline__ short8 pack8(const float* x) {
    S8 H;
    #pragma unroll
    for (int p = 0; p < 4; ++p) {
        union { float f; unsigned int i; } a, b;
        a.f = x[2*p]; b.f = x[2*p+1];
        H.u[p] = ((a.i + 0x8000u) >> 16) | ((b.i + 0x8000u) & 0xFFFF0000u);
    }
    return H.v;
}
__device__ __forceinline__ short8 load8bf(const unsigned short* rowp, int kb,
                                          int kmax, int valid) {
    S8 R;
    if (valid && kb + 8 <= kmax) {
        ushort4 a = *(const ushort4*)(rowp + kb);
        ushort4 b = *(const ushort4*)(rowp + kb + 4);
        R.s[0]=a.x; R.s[1]=a.y; R.s[2]=a.z; R.s[3]=a.w;
        R.s[4]=b.x; R.s[5]=b.y; R.s[6]=b.z; R.s[7]=b.w;
    } else {
        #pragma unroll
        for (int j = 0; j < 8; ++j) {
            int k = kb + j;
            R.s[j] = (valid && k < kmax) ? rowp[k] : (unsigned short)0;
        }
    }
    return R.v;
}
__device__ __forceinline__ short8 loadB(const void* W, int row, int kb, int isbf,
                                        int valid) {
    if (isbf) return load8bf((const unsigned short*)W + row * 300, kb, 300, valid);
    float t[8];
    load8f((const float*)W + row * 300, kb, 300, valid, t);
    return pack8(t);
}

__device__ __forceinline__ int xcd_id() {
    int x;
    asm volatile("s_getreg_b32 %0, hwreg(HW_REG_XCC_ID)" : "=s"(x));
    return x & 7;
}
// relaxed spin until *p >= target; bounded (lost block => visible fail)
__device__ __forceinline__ void spin_ge(int* p, int target) {
    int t = 0;
    while (__hip_atomic_load(p, __ATOMIC_RELAXED, AG) < target) {
        __builtin_amdgcn_s_sleep(1);
        if (++t > 500000) break;
    }
    asm volatile("" ::: "memory");
}

// SYNC slots (int index, 256 B apart):
//   cnt1[mt]  = mt*64           mm1 tiles (target 5)
//   cnt2[b]   = (64+b)*64       mm2 units per batch (target 160)
//   fb[b][x]  = (68+b*8+x)*64   per-XCD fan-out flags
//   cnt3[gt]  = (100+gt)*64     attn rows done per global 16-row tile

// ---------------------------------------------------------------------------
// Fused DiSA, flag-chained, XCD-PAIR batch swizzle (round-11 structure).
// THIS ROUND: attn j-loop rewritten as explicit 16-wide load batches with
// NAMED registers — round-11's VGPR_Count=28 proved the compiler held only
// ~2 of the 8B ED loads in flight, latency-serializing the hottest loop.
// grid 640 x 320 (3 blocks/CU => co-resident).
// ---------------------------------------------------------------------------
__global__ __launch_bounds__(320, 4) void k_fused(
        const void* __restrict__ Xv, const int* __restrict__ mask,
        const void* __restrict__ Wfc, const void* __restrict__ bfc,
        const void* __restrict__ W1,  const void* __restrict__ W2,
        const void* __restrict__ b1v, const void* __restrict__ Wf1,
        const void* __restrict__ Wf2, const void* __restrict__ bfv,
        float* __restrict__ ws, void* __restrict__ outv) {
    __shared__ int s_isbf;
    __shared__ unsigned short vlist[256];
    __shared__ int s_cnt, s_tgt;

    const int tid = threadIdx.x;
    const int blk = blockIdx.x;
    // wave-parallel bf16 detect (1 load latency)
    if (tid < 64) {
        float v = bf2f(((const unsigned short*)Wfc)[tid]);
        int ok = fabsf(v) < 1.0f;
        unsigned long long bal = __ballot(ok);
        if (tid == 0) s_isbf = (bal == ~0ull) ? 1 : 0;
    }
    __syncthreads();
    const int isbf = s_isbf;
    unsigned short* U = (unsigned short*)(ws + U_BASE);
    int* S = (int*)(ws + SYNC_FOFF);
    const int xid = xcd_id();

    // swizzle: batch <-> XCD pair
    const int res = blk & 7;
    const int bat = res >> 1;            // 0..3
    const int li  = ((blk >> 3) << 1) | (res & 1);   // 0..159 within batch
    const int base = bat * 256;

    // ---- Phase 1: mm1  rep = elu(X@Wfc^T + bfc)  (li < 80) ----
    if (li < 80 && tid < 256) {
        const int mt_l = li / 5, nt = li % 5;
        const int mt = bat * 16 + mt_l;
        const int w = tid >> 6, l = tid & 63;
        const int m0 = mt * 16, lm = l & 15, koff = (l >> 4) * 8;
        const int nrow = nt * 64 + w * 16 + lm;          // 0..319
        const int bval = nrow < 300;
        const int ncl = bval ? nrow : 0;
        f32x4 acc = {0.f, 0.f, 0.f, 0.f};
        if (isbf) {
            const unsigned short* Xp = (const unsigned short*)Xv + (m0 + lm) * 300;
            #pragma unroll
            for (int ks = 0; ks < 10; ++ks) {
                short8 a = load8bf(Xp, ks*32 + koff, 300, 1);
                short8 b = loadB(Wfc, ncl, ks*32 + koff, 1, bval);
                acc = __builtin_amdgcn_mfma_f32_16x16x32_bf16(a, b, acc, 0, 0, 0);
            }
        } else {
            const float* Xp = (const float*)Xv + (m0 + lm) * 300;
            #pragma unroll
            for (int ks = 0; ks < 10; ++ks) {
                float t[8]; load8f(Xp, ks*32 + koff, 300, 1, t);
                short8 a = pack8(t);
                short8 b = loadB(Wfc, ncl, ks*32 + koff, 0, bval);
                acc = __builtin_amdgcn_mfma_f32_16x16x32_bf16(a, b, acc, 0, 0, 0);
            }
        }
        if (bval) {
            float bb = ldf(bfc, nrow, isbf);
            #pragma unroll
            for (int r = 0; r < 4; ++r) {
                int mg = m0 + (l >> 4) * 4 + r;
                float v = acc[r] + bb;
                v = v > 0.f ? v : (__expf(v) - 1.f);
                st_wt_f32(ws + ED + (mg * 300 + nrow) * 2 + 1, v);  // ed.y = rep
                st_wt_u16(U + REPB + mg * 320 + nrow, f2bf(v));
            }
        } else {
            #pragma unroll
            for (int r = 0; r < 4; ++r) {
                int mg = m0 + (l >> 4) * 4 + r;
                st_wt_u16(U + REPB + mg * 320 + nrow, 0);
            }
        }
    }
    __syncthreads();                                // drains all waves' vmcnt
    if (li < 80 && tid == 0)
        __hip_atomic_fetch_add(S + (bat * 16 + li / 5) * 64, 1,
                               __ATOMIC_RELAXED, AG);

    // ---- Phase 2: mm2  dep/head = rep @ {W1,W2}^T; one unit per block ----
    {
        const int mt_l = li / 10, nt10 = li % 10;
        const int mt = bat * 16 + mt_l;
        if (tid == 0) spin_ge(S + mt * 64, 5);
        __syncthreads();
        if (tid < 256) {
            const int w = tid >> 6, l = tid & 63;
            const int m0 = mt * 16, lm = l & 15, koff = (l >> 4) * 8;
            const int ng = nt10 * 64 + w * 16 + lm;      // 0..639
            const int wsel = ng < 320;
            const int wrow = wsel ? ng : ng - 320;
            const int bval = wrow < 300;
            const int ncl = bval ? wrow : 0;
            const void* Wsel = wsel ? W1 : W2;
            const unsigned short* ap = U + REPB + (m0 + lm) * 320 + koff;
            f32x4 acc = {0.f, 0.f, 0.f, 0.f};
            #pragma unroll
            for (int ks = 0; ks < 10; ++ks) {
                short8 a = *(const short8*)(ap + ks * 32);
                short8 b = loadB(Wsel, ncl, ks*32 + koff, isbf, bval);
                acc = __builtin_amdgcn_mfma_f32_16x16x32_bf16(a, b, acc, 0, 0, 0);
            }
            if (ng < 300) {
                float bb = ldf(b1v, ng, isbf);
                #pragma unroll
                for (int r = 0; r < 4; ++r) {
                    int mg = m0 + (l >> 4) * 4 + r;
                    st_wt_f32(ws + ED + (mg * 300 + ng) * 2,
                              __expf(0.4f * (acc[r] + bb)));   // ed.x
                }
            } else if (ng >= 320 && ng < 620) {
                #pragma unroll
                for (int r = 0; r < 4; ++r) {
                    int mg = m0 + (l >> 4) * 4 + r;
                    st_wt_f32(ws + HEADF + mg * 300 + (ng - 320), acc[r]);
                }
            }
        }
        __syncthreads();                        // drain before flag
        if (tid == 0) {
            int old = __hip_atomic_fetch_add(S + (64 + bat) * 64, 1,
                                             __ATOMIC_RELAXED, AG);
            if (old == 159) {                   // last mm2 unit of batch
                #pragma unroll
                for (int x = 0; x < 8; ++x)
                    __hip_atomic_store(S + (68 + bat * 8 + x) * 64, 1,
                                       __ATOMIC_RELAXED, AG);
            }
        }
    }

    // ---- Phase 3: attn; compacted valid rows, pair (2*li, 2*li+1).
    //      Explicit 16-wide / 4-wide load batches (named regs) for ILP. ----
    {
        if (tid < 64) {
            int basec = 0;
            #pragma unroll
            for (int c = 0; c < 4; ++c) {
                const int j = c * 64 + tid;
                const int mv = mask[base + j] != 0;
                unsigned long long bal = __ballot(mv);
                int pos = basec + __popcll(bal & ((1ull << tid) - 1ull));
                if (mv) vlist[pos] = (unsigned short)j;
                basec += __popcll(bal);
            }
            if (tid == 0) s_cnt = basec;
        }
        if (tid == 0) spin_ge(S + (68 + bat * 8 + xid) * 64, 1);
        __syncthreads();
        const int cnt = s_cnt;
        const int iu = 2 * li;
        if (iu < cnt) {
            const int ia = vlist[iu];                    // valid row A
            const int hasB = (iu + 1 < cnt);
            const int ib = hasB ? vlist[iu + 1] : ia;    // valid row B
            const int ga = base + ia, gb = base + ib;
            const int d = tid;
            if (d >= 300) {
                st_wt_u16(U + ATB + ga * 320 + d, 0);
                if (hasB) st_wt_u16(U + ATB + gb * 320 + d, 0);
            } else {
                const float pwa = __expf(0.4f * ws[HEADF + ga * 300 + d]);
                const float pwb = __expf(0.4f * ws[HEADF + gb * 300 + d]);
                const float2* ep2 = ((const float2*)(ws + ED)) + base * Dx + d;
                float sa = 0.f, ra = 0.f, sb = 0.f, rb = 0.f;
                if (hasB) {                              // prologue: j=ib, row A only
                    float2 v = ep2[ib * Dx];
                    float ua = fmaf(v.x, pwa, 1.0f);
                    float ea = __expf(-10.0f * __builtin_amdgcn_rcpf(ua));
                    sa += ea; ra = fmaf(ea, v.y, ra);
                }
#define STEP(vv) { \
    float ua_ = fmaf((vv).x, pwa, 1.0f); \
    float ub_ = fmaf((vv).x, pwb, 1.0f); \
    float ea_ = __expf(-10.0f * __builtin_amdgcn_rcpf(ua_)); \
    float eb_ = __expf(-10.0f * __builtin_amdgcn_rcpf(ub_)); \
    sa += ea_; ra = fmaf(ea_, (vv).y, ra); \
    sb += eb_; rb = fmaf(eb_, (vv).y, rb); }
                int t = iu + 2;
                for (; t + 16 <= cnt; t += 16) {     // 16 loads in flight
                    float2 v0  = ep2[(int)vlist[t     ] * Dx];
                    float2 v1  = ep2[(int)vlist[t +  1] * Dx];
                    float2 v2  = ep2[(int)vlist[t +  2] * Dx];
                    float2 v3  = ep2[(int)vlist[t +  3] * Dx];
                    float2 v4  = ep2[(int)vlist[t +  4] * Dx];
                    float2 v5  = ep2[(int)vlist[t +  5] * Dx];
                    float2 v6  = ep2[(int)vlist[t +  6] * Dx];
                    float2 v7  = ep2[(int)vlist[t +  7] * Dx];
                    float2 v8  = ep2[(int)vlist[t +  8] * Dx];
                    float2 v9  = ep2[(int)vlist[t +  9] * Dx];
                    float2 v10 = ep2[(int)vlist[t + 10] * Dx];
                    float2 v11 = ep2[(int)vlist[t + 11] * Dx];
                    float2 v12 = ep2[(int)vlist[t + 12] * Dx];
                    float2 v13 = ep2[(int)vlist[t + 13] * Dx];
                    float2 v14 = ep2[(int)vlist[t + 14] * Dx];
                    float2 v15 = ep2[(int)vlist[t + 15] * Dx];
                    STEP(v0)  STEP(v1)  STEP(v2)  STEP(v3)
                    STEP(v4)  STEP(v5)  STEP(v6)  STEP(v7)
                    STEP(v8)  STEP(v9)  STEP(v10) STEP(v11)
                    STEP(v12) STEP(v13) STEP(v14) STEP(v15)
                }
                for (; t + 4 <= cnt; t += 4) {       // 4-wide mid
                    float2 v0 = ep2[(int)vlist[t    ] * Dx];
                    float2 v1 = ep2[(int)vlist[t + 1] * Dx];
                    float2 v2 = ep2[(int)vlist[t + 2] * Dx];
                    float2 v3 = ep2[(int)vlist[t + 3] * Dx];
                    STEP(v0) STEP(v1) STEP(v2) STEP(v3)
                }
                for (; t < cnt; ++t) {               // scalar tail
                    float2 v0 = ep2[(int)vlist[t] * Dx];
                    STEP(v0)
                }
#undef STEP
                const float dena = sa + (sa == 0.f ? 1.f : 0.f) + 1e-20f;
                const float aa = ra / dena;
                st_wt_f32(ws + ATTNF + ga * Dx + d, aa);
                st_wt_u16(U + ATB + ga * 320 + d, f2bf(aa));
                if (hasB) {
                    const float denb = sb + (sb == 0.f ? 1.f : 0.f) + 1e-20f;
                    const float ab = rb / denb;
                    st_wt_f32(ws + ATTNF + gb * Dx + d, ab);
                    st_wt_u16(U + ATB + gb * 320 + d, f2bf(ab));
                }
            }
            __syncthreads();                    // drain before row flags
            if (tid == 0) {
                __hip_atomic_fetch_add(S + (100 + (ga >> 4)) * 64, 1,
                                       __ATOMIC_RELAXED, AG);
                if (hasB)
                    __hip_atomic_fetch_add(S + (100 + (gb >> 4)) * 64, 1,
                                           __ATOMIC_RELAXED, AG);
            }
        }
    }

    // ---- Phase 4: mm3 (li < 80); gate = data-dependent valid count ----
    if (li < 80) {
        const int mt3 = bat * 16 + li / 5, nt3 = li % 5;
        const int m0 = mt3 * 16;
        if (tid < 64) {
            int mv = (tid < 16) ? (mask[m0 + tid] != 0) : 0;
            unsigned long long bal = __ballot(mv);
            if (tid == 0) s_tgt = (int)__popcll(bal);
        }
        __syncthreads();
        const int tgt = s_tgt;
        if (tid == 0 && tgt > 0) spin_ge(S + (100 + mt3) * 64, tgt);
        __syncthreads();
        if (tid < 256) {
            const int w = tid >> 6, l = tid & 63;
            const int lm = l & 15, koff = (l >> 4) * 8;
            const int nrow = nt3 * 64 + w * 16 + lm;     // 0..319
            const int bval = nrow < 300;
            const int ncl = bval ? nrow : 0;
            const unsigned short* a1p = U + REPB + (m0 + lm) * 320 + koff;
            const unsigned short* a2p = U + ATB  + (m0 + lm) * 320 + koff;
            f32x4 acc = {0.f, 0.f, 0.f, 0.f};
            #pragma unroll
            for (int ks = 0; ks < 10; ++ks) {
                short8 a = *(const short8*)(a1p + ks * 32);
                short8 bB = loadB(Wf1, ncl, ks*32 + koff, isbf, bval);
                acc = __builtin_amdgcn_mfma_f32_16x16x32_bf16(a, bB, acc, 0, 0, 0);
            }
            #pragma unroll
            for (int ks = 0; ks < 10; ++ks) {
                short8 a = *(const short8*)(a2p + ks * 32);
                short8 bB = loadB(Wf2, ncl, ks*32 + koff, isbf, bval);
                acc = __builtin_amdgcn_mfma_f32_16x16x32_bf16(a, bB, acc, 0, 0, 0);
            }
            if (bval) {
                float bb = ldf(bfv, nrow, isbf);
                #pragma unroll
                for (int r = 0; r < 4; ++r) {
                    int mg = m0 + (l >> 4) * 4 + r;
                    float res2 = 0.f;
                    if (mask[mg]) {
                        float gp = acc[r] + bb;
                        float gate = 1.0f / (1.0f + __expf(-gp));
                        float rv = ws[ED + (mg * 300 + nrow) * 2 + 1];
                        float av = ws[ATTNF + mg * 300 + nrow];
                        res2 = gate * rv + (1.0f - gate) * av;
                    }
                    if (isbf) ((__hip_bfloat16*)outv)[mg * 300 + nrow] = __float2bfloat16(res2);
                    else      ((float*)outv)[mg * 300 + nrow] = res2;
                }
            }
        }
    }
}

extern "C" void kernel_launch(void* const* d_in, const int* in_sizes, int n_in,
                              void* d_out, int out_size, void* d_ws, size_t ws_size,
                              hipStream_t stream) {
    const void* X   = d_in[0];
    const int*  msk = (const int*)d_in[1];
    const void* Wfc = d_in[2];
    const void* bfc = d_in[3];
    const void* W1  = d_in[4];
    const void* W2  = d_in[5];
    const void* b1  = d_in[6];
    const void* Wf1 = d_in[7];
    const void* Wf2 = d_in[8];
    const void* bfv = d_in[9];
    float* ws = (float*)d_ws;

    // zero the flag state (192 slots x 256 B)
    hipMemsetAsync((char*)d_ws + (size_t)SYNC_FOFF * sizeof(float), 0, 49152, stream);

    hipLaunchKernelGGL(k_fused, dim3(640), dim3(320), 0, stream,
                       X, msk, Wfc, bfc, W1, W2, b1, Wf1, Wf2, bfv, ws, d_out);
}